// Round 2
// baseline (718.689 us; speedup 1.0000x reference)
//
#include <hip/hip_runtime.h>
#include <math.h>

#define BB 64
#define SS 2048
#define HH 1024
#define LL 15

// ---------------- span-mean + tanh + zero-init of downstream buffers ----------------
// grid: (64 b, 2 part), 256 threads, float4 over h (each thread owns 4 h-values).
// part 0: cls row tanh + span-1 mean + zero h_cat slice.
// part 1: span-2 mean + zero h1/h2 slices.
// (zeroing replaces a separate memset; downstream GEMMs accumulate atomically)
__global__ void span_tanh_kernel(const float* __restrict__ x,
                                 const int* __restrict__ eidx,
                                 float* __restrict__ t_cat,
                                 float* __restrict__ h_cat,
                                 float* __restrict__ h1,
                                 float* __restrict__ h2) {
  int b = blockIdx.x;
  int part = blockIdx.y;
  int tid = threadIdx.x;
  int h4 = tid * 4;  // 256 threads * 4 = 1024 h
  const float* xb = x + (size_t)b * SS * HH;
  float* tb = t_cat + (size_t)b * 3 * HH;
  const float4 zero4 = {0.f, 0.f, 0.f, 0.f};

  if (part == 0) {
    float4* z = (float4*)(h_cat + (size_t)b * 3 * HH);
    z[tid] = zero4; z[tid + 256] = zero4; z[tid + 512] = zero4;

    int s1 = eidx[b * 4 + 0], e1 = eidx[b * 4 + 1];
    float c1 = (float)max(e1 - s1, 1);
    float4 v0 = *(const float4*)&xb[h4];
    float4 a = zero4;
    for (int s = s1; s < e1; ++s) {
      float4 v = *(const float4*)&xb[(size_t)s * HH + h4];
      a.x += v.x; a.y += v.y; a.z += v.z; a.w += v.w;
    }
    float4 o0 = {tanhf(v0.x), tanhf(v0.y), tanhf(v0.z), tanhf(v0.w)};
    *(float4*)&tb[h4] = o0;
    float4 o1 = {tanhf(a.x / c1), tanhf(a.y / c1), tanhf(a.z / c1), tanhf(a.w / c1)};
    *(float4*)&tb[HH + h4] = o1;
  } else {
    ((float4*)(h1 + (size_t)b * HH))[tid] = zero4;
    ((float4*)(h2 + (size_t)b * HH))[tid] = zero4;

    int s2 = eidx[b * 4 + 2], e2 = eidx[b * 4 + 3];
    float c2 = (float)max(e2 - s2, 1);
    float4 a = zero4;
    for (int s = s2; s < e2; ++s) {
      float4 v = *(const float4*)&xb[(size_t)s * HH + h4];
      a.x += v.x; a.y += v.y; a.z += v.z; a.w += v.w;
    }
    float4 o2 = {tanhf(a.x / c2), tanhf(a.y / c2), tanhf(a.z / c2), tanhf(a.w / c2)};
    *(float4*)&tb[2 * HH + h4] = o2;
  }
}

// ---------------- 64x64 GEMM tile, k-major LDS, register double-buffer ----------------
// C[0:64, j0:j0+64] += A[0:64, k0:kend] @ W[k0:kend, j0:j0+64]  (atomic accumulate)
// 256 threads as 16x16, each a 4x4 micro-tile. LDS stride 68 keeps float4 alignment
// (68*4=272 B, mult of 16) while breaking power-of-2 bank strides.
#define LSTR 68
__device__ __forceinline__ void gemm_tile_body(
    const float* __restrict__ A, int lda,
    const float* __restrict__ W, int ldw,
    const float* __restrict__ bias,
    float* __restrict__ C, int ldc,
    int k0, int kend, int j0, bool addBias) {
  __shared__ float As[32 * LSTR];  // [kk][row]
  __shared__ float Ws[32 * LSTR];  // [kk][col]
  int tid = threadIdx.x;
  int tx = tid & 15, ty = tid >> 4;

  // A-load assignment: idx = tid + i*256 -> row = idx&63, kq = idx>>6 (float4 over k)
  // W-load assignment: idx = tid + i*256 -> row = idx>>4,  cq = idx&15 (float4 over cols)
  float4 aReg[2], wReg[2];
  int aRow[2], aKq[2], wRow[2], wCq[2];
#pragma unroll
  for (int i = 0; i < 2; ++i) {
    int idx = tid + i * 256;
    aRow[i] = idx & 63; aKq[i] = idx >> 6;
    wRow[i] = idx >> 4; wCq[i] = idx & 15;
  }

  auto loadRegs = [&](int kb) {
#pragma unroll
    for (int i = 0; i < 2; ++i) {
      aReg[i] = *(const float4*)&A[(size_t)aRow[i] * lda + kb + 4 * aKq[i]];
      wReg[i] = *(const float4*)&W[(size_t)(kb + wRow[i]) * ldw + j0 + 4 * wCq[i]];
    }
  };

  float acc[4][4] = {{0.f}};
  loadRegs(k0);
  for (int kb = k0; kb < kend; kb += 32) {
    // stage regs -> LDS (k-major; A transposed during store)
#pragma unroll
    for (int i = 0; i < 2; ++i) {
      float av[4] = {aReg[i].x, aReg[i].y, aReg[i].z, aReg[i].w};
#pragma unroll
      for (int j = 0; j < 4; ++j) As[(4 * aKq[i] + j) * LSTR + aRow[i]] = av[j];
      *(float4*)&Ws[wRow[i] * LSTR + 4 * wCq[i]] = wReg[i];
    }
    __syncthreads();
    if (kb + 32 < kend) loadRegs(kb + 32);  // prefetch next k-block while computing
#pragma unroll
    for (int kk = 0; kk < 32; ++kk) {
      float4 a4 = *(const float4*)&As[kk * LSTR + ty * 4];
      float4 w4 = *(const float4*)&Ws[kk * LSTR + tx * 4];
      float a[4] = {a4.x, a4.y, a4.z, a4.w};
      float w[4] = {w4.x, w4.y, w4.z, w4.w};
#pragma unroll
      for (int i = 0; i < 4; ++i)
#pragma unroll
        for (int j = 0; j < 4; ++j) acc[i][j] += a[i] * w[j];
    }
    __syncthreads();
  }
#pragma unroll
  for (int i = 0; i < 4; ++i) {
    int r = ty * 4 + i;
#pragma unroll
    for (int j = 0; j < 4; ++j) {
      int c = j0 + tx * 4 + j;
      float v = acc[i][j];
      if (addBias) v += bias[c];
      atomicAdd(&C[(size_t)r * ldc + c], v);
    }
  }
}

// Block-diagonal stage: 3 branches (cls/subj/obj), blockIdx.z selects branch.
__global__ void gemm_bd_kernel(const float* __restrict__ t_cat,
                               const float* __restrict__ Wc, const float* __restrict__ bc,
                               const float* __restrict__ We1, const float* __restrict__ be1,
                               const float* __restrict__ We2, const float* __restrict__ be2,
                               float* __restrict__ h_cat, int Kchunk) {
  int z = blockIdx.z;
  const float* W = (z == 0) ? Wc : ((z == 1) ? We1 : We2);
  const float* bias = (z == 0) ? bc : ((z == 1) ? be1 : be2);
  const float* A = t_cat + z * HH;
  float* C = h_cat + z * HH;
  int k0 = blockIdx.y * Kchunk;
  gemm_tile_body(A, 3 * HH, W, HH, bias, C, 3 * HH,
                 k0, k0 + Kchunk, blockIdx.x * 64, blockIdx.y == 0);
}

// Plain split-K GEMM: grid (N/64, KSPLIT)
__global__ void gemm_kernel(const float* __restrict__ A, int lda,
                            const float* __restrict__ W, int ldw,
                            const float* __restrict__ bias,
                            float* __restrict__ C, int ldc, int Kchunk) {
  int k0 = blockIdx.y * Kchunk;
  gemm_tile_body(A, lda, W, ldw, bias, C, ldc,
                 k0, k0 + Kchunk, blockIdx.x * 64, blockIdx.y == 0);
}

// ---------------- final 1024 -> 15: one wave per output ----------------
// 960 outputs = 960 waves = 240 blocks of 256
__global__ void out_kernel(const float* __restrict__ h2,
                           const float* __restrict__ Wout,
                           const float* __restrict__ bout,
                           float* __restrict__ out) {
  int tid = threadIdx.x;
  int lane = tid & 63;
  int idx = blockIdx.x * 4 + (tid >> 6);
  int b = idx / LL, l = idx % LL;
  const float* h = h2 + (size_t)b * HH;
  float acc = 0.f;
#pragma unroll
  for (int w = 0; w < 4; ++w) {
    int k0 = (w * 64 + lane) * 4;
    float4 h4 = *(const float4*)&h[k0];
    acc += h4.x * Wout[(size_t)(k0 + 0) * LL + l];
    acc += h4.y * Wout[(size_t)(k0 + 1) * LL + l];
    acc += h4.z * Wout[(size_t)(k0 + 2) * LL + l];
    acc += h4.w * Wout[(size_t)(k0 + 3) * LL + l];
  }
#pragma unroll
  for (int off = 32; off > 0; off >>= 1) acc += __shfl_down(acc, off, 64);
  if (lane == 0) out[idx] = acc + bout[l];
}

extern "C" void kernel_launch(void* const* d_in, const int* in_sizes, int n_in,
                              void* d_out, int out_size, void* d_ws, size_t ws_size,
                              hipStream_t stream) {
  const float* x     = (const float*)d_in[0];
  const int*   eidx  = (const int*)d_in[1];
  const float* W_cls = (const float*)d_in[2];
  const float* b_cls = (const float*)d_in[3];
  const float* W_e1  = (const float*)d_in[4];
  const float* b_e1  = (const float*)d_in[5];
  const float* W_e2  = (const float*)d_in[6];
  const float* b_e2  = (const float*)d_in[7];
  const float* W1    = (const float*)d_in[8];
  const float* b1    = (const float*)d_in[9];
  const float* W2    = (const float*)d_in[10];
  const float* b2    = (const float*)d_in[11];
  const float* Wout  = (const float*)d_in[12];
  const float* bout  = (const float*)d_in[13];
  float* out = (float*)d_out;

  float* ws    = (float*)d_ws;
  float* t_cat = ws;                          // 64*3072
  float* h_cat = t_cat + BB * 3 * HH;         // 64*3072 (atomic-accumulated)
  float* h1    = h_cat + BB * 3 * HH;         // 64*1024 (atomic-accumulated)
  float* h2    = h1 + BB * HH;                // 64*1024 (atomic-accumulated)

  // K1: span means + tanh (float4, one span per block) + zero-init (128 blocks)
  span_tanh_kernel<<<dim3(BB, 2), 256, 0, stream>>>(x, eidx, t_cat, h_cat, h1, h2);

  // K2: block-diag [64,3072] -> [64,3072]; K=1024, KS=8 (Kchunk 128) -> 384 blocks
  gemm_bd_kernel<<<dim3(16, 8, 3), 256, 0, stream>>>(
      t_cat, W_cls, b_cls, W_e1, b_e1, W_e2, b_e2, h_cat, 128);

  // K3: [64,3072] @ [3072,1024]; K=3072, KS=24 (Kchunk 128) -> 384 blocks
  gemm_kernel<<<dim3(16, 24, 1), 256, 0, stream>>>(h_cat, 3 * HH, W1, HH, b1, h1, HH, 128);

  // K4: [64,1024] @ [1024,1024]; K=1024, KS=16 (Kchunk 64) -> 256 blocks
  gemm_kernel<<<dim3(16, 16, 1), 256, 0, stream>>>(h1, HH, W2, HH, b2, h2, HH, 64);

  // K5: [64,1024] @ [1024,15]; wave-per-output
  out_kernel<<<dim3(240), 256, 0, stream>>>(h2, Wout, bout, out);
}